// Round 5
// baseline (374.057 us; speedup 1.0000x reference)
//
#include <hip/hip_runtime.h>
#include <math.h>

typedef __attribute__((ext_vector_type(8))) short bf16x8;
typedef __attribute__((ext_vector_type(4))) float f32x4;
typedef unsigned short ushort_t;

#define SQRT_D 11.313708498984761f
#define INV_SQRT_D 0.08838834764831845f

__device__ __forceinline__ unsigned short f2b(float f) {
    unsigned u = __float_as_uint(f);
    unsigned r = (u + 0x7fffu + ((u >> 16) & 1u)) >> 16;
    return (unsigned short)r;
}
__device__ __forceinline__ float b2f(unsigned short h) {
    return __uint_as_float(((unsigned)h) << 16);
}

__device__ __forceinline__ void async_copy16(const void* g, void* l) {
    __builtin_amdgcn_global_load_lds((const __attribute__((address_space(1))) void*)g,
                                     (__attribute__((address_space(3))) void*)l, 16, 0, 0);
}

// ---------------------------------------------------------------------------
// prep: z<4 -> transpose W_z to bf16 WT4[z]; z==4 -> convert X to bf16; block
// (0,0,4) additionally runs splat_prep on its first 128 threads.
// ---------------------------------------------------------------------------
__global__ __launch_bounds__(256) void prep(
    const float* __restrict__ X, const float* __restrict__ W0,
    const float* __restrict__ W1, const float* __restrict__ W2,
    const float* __restrict__ W3, const float* __restrict__ sp,
    const float* __restrict__ sd, const float* __restrict__ ls,
    const float* __restrict__ la, ushort_t* __restrict__ Xbf,
    ushort_t* __restrict__ WT4, float* __restrict__ posn,
    float* __restrict__ dirn, float* __restrict__ pos_sq,
    float* __restrict__ pdv, float* __restrict__ iv2s2,
    float* __restrict__ amp) {
    __shared__ float t[32][33];
    const int z = blockIdx.z;
    if (z < 4) {
        const float* W = (z == 0) ? W0 : (z == 1) ? W1 : (z == 2) ? W2 : W3;
        ushort_t* WT = WT4 + (size_t)z * 4194304;
        int tx = threadIdx.x & 31, ty = threadIdx.x >> 5;
        int bn = blockIdx.x * 32, bk = blockIdx.y * 32;
#pragma unroll
        for (int i = 0; i < 4; ++i)
            t[ty + i * 8][tx] = W[(size_t)(bk + ty + i * 8) * 2048 + bn + tx];
        __syncthreads();
#pragma unroll
        for (int i = 0; i < 4; ++i)
            WT[(size_t)(bn + ty + i * 8) * 2048 + bk + tx] = f2b(t[tx][ty + i * 8]);
        return;
    }
    // convert X
    {
        int bi = blockIdx.y * 64 + blockIdx.x;
        int i = (bi * 256 + threadIdx.x) * 4;
        float4 v = *(const float4*)(X + i);
        ushort4 o;
        o.x = f2b(v.x); o.y = f2b(v.y); o.z = f2b(v.z); o.w = f2b(v.w);
        *(ushort4*)(Xbf + i) = o;
    }
    // splat prep (one block only)
    if (blockIdx.x == 0 && blockIdx.y == 0 && threadIdx.x < 128) {
        int i = threadIdx.x;
        const float* p = sp + (size_t)i * 128;
        const float* d = sd + (size_t)i * 128;
        float np_ = 0.f, nd_ = 0.f;
        for (int k = 0; k < 128; ++k) { np_ += p[k] * p[k]; nd_ += d[k] * d[k]; }
        np_ = sqrtf(np_); nd_ = sqrtf(nd_);
        const float sc = 3.394112549695428f;  // sqrt(128)*0.3
        float rp = sc / (np_ + 1e-12f);
        float rd = 1.f / (nd_ + 1e-12f);
        float psq = 0.f, pd_ = 0.f;
        for (int k = 0; k < 128; ++k) {
            float pn = p[k] * rp;
            float dn = d[k] * rd;
            posn[(size_t)i * 128 + k] = pn;
            dirn[(size_t)i * 128 + k] = dn;
            psq += pn * pn;
            pd_ += pn * dn;
        }
        pos_sq[i] = psq;
        pdv[i] = pd_;
        float s = expf(ls[i]);
        s = fminf(fmaxf(s, 0.3f), 1.2f);
        iv2s2[i] = 0.5f / (s * s);
        if ((i & 7) == 0) {
            int h = i >> 3;
            float mx = -INFINITY;
            for (int n = 0; n < 8; ++n) mx = fmaxf(mx, la[h * 8 + n]);
            float e[8]; float ssum = 0.f;
            for (int n = 0; n < 8; ++n) { e[n] = expf(la[h * 8 + n] - mx); ssum += e[n]; }
            for (int n = 0; n < 8; ++n) amp[h * 8 + n] = e[n] / ssum;
        }
    }
}

// LDS chunk swizzle (64 B rows, 4x16B chunks): phys = c ^ ((r + (r>>2)) & 3).

// ---------------------------------------------------------------------------
// gemm_qkv: fused Q/K/V projection, single-barrier double-buffered staging.
// grid (16,48); which = blockIdx.y>>4. Q scaled by 1/sqrt(D); V also [b,h,d,s].
// ---------------------------------------------------------------------------
__global__ __launch_bounds__(256) void gemm_qkv(const ushort_t* __restrict__ A,
                                                const ushort_t* __restrict__ WT4,
                                                ushort_t* __restrict__ Qb,
                                                ushort_t* __restrict__ Kb,
                                                ushort_t* __restrict__ Vb,
                                                ushort_t* __restrict__ Vt) {
    __shared__ ushort_t As[2][128 * 32];
    __shared__ ushort_t Bs[2][128 * 32];
    const int tid = threadIdx.x, lane = tid & 63, wave = tid >> 6;
    const int l15 = lane & 15, quad = lane >> 4;
    const int wm = (wave >> 1) * 64, wn = (wave & 1) * 64;
    const int bm = blockIdx.x * 128;
    const int by = blockIdx.y, which = by >> 4, bn = (by & 15) * 128;
    const ushort_t* BT = WT4 + (size_t)which * 4194304;
    f32x4 acc[4][4] = {};
    const int off0 = tid * 16;
    const int row0 = tid >> 2;
    const int c0 = (tid & 3) ^ ((row0 + (row0 >> 2)) & 3);
    const ushort_t* ga = A + (size_t)(bm + row0) * 2048 + c0 * 8;
    const ushort_t* gb = BT + (size_t)(bn + row0) * 2048 + c0 * 8;
    const int rsw = (l15 + (l15 >> 2)) & 3;
#define STAGEG(buf_, k_)                                                      \
    {                                                                         \
        async_copy16(ga + (k_), (char*)As[buf_] + off0);                      \
        async_copy16(ga + (size_t)64 * 2048 + (k_), (char*)As[buf_] + off0 + 4096); \
        async_copy16(gb + (k_), (char*)Bs[buf_] + off0);                      \
        async_copy16(gb + (size_t)64 * 2048 + (k_), (char*)Bs[buf_] + off0 + 4096); \
    }
    STAGEG(0, 0);
    for (int k0 = 0; k0 < 2048; k0 += 32) {
        __syncthreads();
        if (k0 < 2016) STAGEG(((k0 >> 5) + 1) & 1, k0 + 32);
        const int cb = (k0 >> 5) & 1;
        bf16x8 af[4], bfr[4];
#pragma unroll
        for (int i = 0; i < 4; ++i)
            af[i] = *(const bf16x8*)((const char*)As[cb] + (wm + i * 16 + l15) * 64 + ((quad ^ rsw) << 4));
#pragma unroll
        for (int j = 0; j < 4; ++j)
            bfr[j] = *(const bf16x8*)((const char*)Bs[cb] + (wn + j * 16 + l15) * 64 + ((quad ^ rsw) << 4));
#pragma unroll
        for (int i = 0; i < 4; ++i)
#pragma unroll
            for (int j = 0; j < 4; ++j)
                acc[i][j] = __builtin_amdgcn_mfma_f32_16x16x32_bf16(af[i], bfr[j], acc[i][j], 0, 0, 0);
    }
#undef STAGEG
    ushort_t* Cb = (which == 0) ? Qb : ((which == 1) ? Kb : Vb);
    const bool dot = (which == 2);
    const float oscale = (which == 0) ? INV_SQRT_D : 1.f;
#pragma unroll
    for (int i = 0; i < 4; ++i) {
#pragma unroll
        for (int j = 0; j < 4; ++j) {
            int m0 = bm + wm + i * 16 + quad * 4;
            int n = bn + wn + j * 16 + l15;
            int b = m0 >> 10, s0 = m0 & 1023, h = n >> 7, d = n & 127;
            ushort4 pack;
            unsigned short* pp = (unsigned short*)&pack;
#pragma unroll
            for (int r = 0; r < 4; ++r) {
                unsigned short bv = f2b(acc[i][j][r] * oscale);
                pp[r] = bv;
                Cb[((size_t)((b << 4) | h) * 1024 + (s0 + r)) * 128 + d] = bv;
            }
            if (dot) *(ushort4*)(Vt + ((size_t)((b << 4) | h) * 128 + d) * 1024 + s0) = pack;
        }
    }
}

// ---------------------------------------------------------------------------
// gemm_out: C(fp32) = A(bf16) @ BT^T. 128x64 tile, dbuf single-barrier.
// ---------------------------------------------------------------------------
__global__ __launch_bounds__(256) void gemm_out(const ushort_t* __restrict__ A,
                                                const ushort_t* __restrict__ BT,
                                                float* __restrict__ Cf) {
    __shared__ ushort_t As[2][128 * 32];
    __shared__ ushort_t Bs[2][64 * 32];
    const int tid = threadIdx.x, lane = tid & 63, wave = tid >> 6;
    const int l15 = lane & 15, quad = lane >> 4;
    const int wm = (wave >> 1) * 64, wn = (wave & 1) * 32;
    const int bm = blockIdx.x * 128, bn = blockIdx.y * 64;
    f32x4 acc[4][2] = {};
    const int off0 = tid * 16;
    const int row0 = tid >> 2;
    const int c0 = (tid & 3) ^ ((row0 + (row0 >> 2)) & 3);
    const ushort_t* ga = A + (size_t)(bm + row0) * 2048 + c0 * 8;
    const ushort_t* gb = BT + (size_t)(bn + row0) * 2048 + c0 * 8;
    const int rsw = (l15 + (l15 >> 2)) & 3;
#define STAGEO(buf_, k_)                                                      \
    {                                                                         \
        async_copy16(ga + (k_), (char*)As[buf_] + off0);                      \
        async_copy16(ga + (size_t)64 * 2048 + (k_), (char*)As[buf_] + off0 + 4096); \
        async_copy16(gb + (k_), (char*)Bs[buf_] + off0);                      \
    }
    STAGEO(0, 0);
    for (int k0 = 0; k0 < 2048; k0 += 32) {
        __syncthreads();
        if (k0 < 2016) STAGEO(((k0 >> 5) + 1) & 1, k0 + 32);
        const int cb = (k0 >> 5) & 1;
        bf16x8 af[4], bfr[2];
#pragma unroll
        for (int i = 0; i < 4; ++i)
            af[i] = *(const bf16x8*)((const char*)As[cb] + (wm + i * 16 + l15) * 64 + ((quad ^ rsw) << 4));
#pragma unroll
        for (int j = 0; j < 2; ++j)
            bfr[j] = *(const bf16x8*)((const char*)Bs[cb] + (wn + j * 16 + l15) * 64 + ((quad ^ rsw) << 4));
#pragma unroll
        for (int i = 0; i < 4; ++i)
#pragma unroll
            for (int j = 0; j < 2; ++j)
                acc[i][j] = __builtin_amdgcn_mfma_f32_16x16x32_bf16(af[i], bfr[j], acc[i][j], 0, 0, 0);
    }
#undef STAGEO
#pragma unroll
    for (int i = 0; i < 4; ++i)
#pragma unroll
        for (int j = 0; j < 2; ++j)
#pragma unroll
            for (int r = 0; r < 4; ++r) {
                int m = bm + wm + i * 16 + quad * 4 + r;
                int n = bn + wn + j * 16 + l15;
                Cf[(size_t)m * 2048 + n] = acc[i][j][r];
            }
}

// ---------------------------------------------------------------------------
// affinity_k: ka [B,NH,S,NS] only (qa is fused into flash_blend).
// ---------------------------------------------------------------------------
__global__ __launch_bounds__(256) void affinity_k(
    const ushort_t* __restrict__ K,
    const float* __restrict__ posn, const float* __restrict__ dirn,
    const float* __restrict__ pos_sq, const float* __restrict__ pdv,
    const float* __restrict__ iv2s2, const float* __restrict__ ds_in,
    float* __restrict__ ka) {
    int gid = blockIdx.x * 256 + threadIdx.x;
    int n = gid & 7;
    int t = gid >> 3;  // 0..32767
    const ushort_t* T = K + (size_t)t * 128;
    int h = (t >> 10) & 15;
    const float* P = posn + (size_t)(h * 8 + n) * 128;
    const float* Dr = dirn + (size_t)(h * 8 + n) * 128;
    float tsq = 0.f, tp = 0.f, td = 0.f;
#pragma unroll
    for (int d = 0; d < 128; d += 8) {
        uint4 raw = *(const uint4*)(T + d);
        float tv[8];
        tv[0] = __uint_as_float(raw.x << 16); tv[1] = __uint_as_float(raw.x & 0xffff0000u);
        tv[2] = __uint_as_float(raw.y << 16); tv[3] = __uint_as_float(raw.y & 0xffff0000u);
        tv[4] = __uint_as_float(raw.z << 16); tv[5] = __uint_as_float(raw.z & 0xffff0000u);
        tv[6] = __uint_as_float(raw.w << 16); tv[7] = __uint_as_float(raw.w & 0xffff0000u);
        float4 p0 = *(const float4*)(P + d), p1 = *(const float4*)(P + d + 4);
        float4 d0 = *(const float4*)(Dr + d), d1 = *(const float4*)(Dr + d + 4);
        tsq += tv[0]*tv[0]+tv[1]*tv[1]+tv[2]*tv[2]+tv[3]*tv[3]+tv[4]*tv[4]+tv[5]*tv[5]+tv[6]*tv[6]+tv[7]*tv[7];
        tp  += tv[0]*p0.x+tv[1]*p0.y+tv[2]*p0.z+tv[3]*p0.w+tv[4]*p1.x+tv[5]*p1.y+tv[6]*p1.z+tv[7]*p1.w;
        td  += tv[0]*d0.x+tv[1]*d0.y+tv[2]*d0.z+tv[3]*d0.w+tv[4]*d1.x+tv[5]*d1.y+tv[6]*d1.z+tv[7]*d1.w;
    }
    float dist2 = fmaxf(tsq - 2.f * tp + pos_sq[h * 8 + n], 0.f);
    float proj = td - pdv[h * 8 + n];
    float perp2 = fmaxf(dist2 - proj * proj, 0.f);
    float iv = iv2s2[h * 8 + n];
    float dsv = 1.f / (1.f + __expf(-ds_in[0]));
    float aff = (1.f - dsv) * __expf(-dist2 * iv) + dsv * __expf(-perp2 * iv);
    ka[(size_t)t * 8 + n] = aff;
}

// ---------------------------------------------------------------------------
// kv_s1_part: partial KV/S1 over a 128-row S-chunk. grid (32 bh, 8 sc).
// ---------------------------------------------------------------------------
__global__ __launch_bounds__(128) void kv_s1_part(const float* __restrict__ ka,
                                                  const ushort_t* __restrict__ V,
                                                  float* __restrict__ KVp,
                                                  float* __restrict__ S1p) {
    int bh = blockIdx.x, sc = blockIdx.y;
    int d = threadIdx.x;
    const float* kaB = ka + ((size_t)bh * 1024 + sc * 128) * 8;
    const ushort_t* VB = V + ((size_t)bh * 1024 + sc * 128) * 128;
    float acc[8] = {};
#pragma unroll 4
    for (int s = 0; s < 128; ++s) {
        float vd = b2f(VB[(size_t)s * 128 + d]);
        float4 k0 = *(const float4*)(kaB + (size_t)s * 8);
        float4 k1 = *(const float4*)(kaB + (size_t)s * 8 + 4);
        acc[0] += k0.x * vd; acc[1] += k0.y * vd; acc[2] += k0.z * vd; acc[3] += k0.w * vd;
        acc[4] += k1.x * vd; acc[5] += k1.y * vd; acc[6] += k1.z * vd; acc[7] += k1.w * vd;
    }
#pragma unroll
    for (int n = 0; n < 8; ++n) KVp[(((size_t)bh * 8 + n) * 8 + sc) * 128 + d] = acc[n];
    __shared__ float s1p[128];
    {
        int n = d >> 4, chunk = d & 15;
        float p = 0.f;
        for (int s = chunk * 8; s < chunk * 8 + 8; ++s) p += kaB[(size_t)s * 8 + n];
        s1p[d] = p;
    }
    __syncthreads();
    if (d < 8) {
        float t = 0.f;
        for (int c = 0; c < 16; ++c) t += s1p[(d << 4) + c];
        S1p[((size_t)bh * 8 + d) * 8 + sc] = t;
    }
}

// ---------------------------------------------------------------------------
// flash_blend: grid (16 qt, 32 bh). 64 Q-rows/block, K-tile 64, dbuf staging,
// one barrier/iter, flat softmax (scores bounded), qa computed IN-KERNEL from
// the register-resident Q fragments (quad-shfl reduced), parked in LDS.
// ---------------------------------------------------------------------------
__global__ __launch_bounds__(256) void flash_blend(
    const ushort_t* __restrict__ Qg, const ushort_t* __restrict__ Kg,
    const ushort_t* __restrict__ Vtg,
    const float* __restrict__ posn, const float* __restrict__ dirn,
    const float* __restrict__ pos_sq, const float* __restrict__ pdv,
    const float* __restrict__ iv2s2, const float* __restrict__ ds_in,
    const float* __restrict__ amp,
    const float* __restrict__ S1p, const float* __restrict__ KVp,
    const float* __restrict__ gstr, ushort_t* __restrict__ blended) {
    __shared__ ushort_t Ks[2][64 * 128];   // [key][d], chunks swizzled ^(key&15)
    __shared__ ushort_t Vt[2][128 * 64];   // [d][key], chunks swizzled ^(d&7)
    __shared__ ushort_t Ps[4][16 * 72];    // wave-private P
    __shared__ float KVs[8 * 128];
    __shared__ float S1s[8];
    __shared__ float qas[4][16][8];        // per-wave qa
    const int tid = threadIdx.x, lane = tid & 63, wave = tid >> 6;
    const int l15 = lane & 15, quad = lane >> 4;
    const int bh = blockIdx.y, qt = blockIdx.x;
    const int h = bh & 15;

    const ushort_t* Qrow = Qg + ((size_t)(bh * 1024 + qt * 64 + wave * 16 + l15)) * 128 + quad * 8;
    bf16x8 aq[4];
#pragma unroll
    for (int k4 = 0; k4 < 4; ++k4) aq[k4] = *(const bf16x8*)(Qrow + k4 * 32);

    // ---- fused qa: dots over this lane's 32 d-values, then quad-reduce ----
    {
        float tsq = 0.f, tp[8] = {}, td[8] = {};
#pragma unroll
        for (int k4 = 0; k4 < 4; ++k4) {
#pragma unroll
            for (int j = 0; j < 8; ++j) {
                float qv = b2f((unsigned short)aq[k4][j]) * SQRT_D;  // undo prescale
                int d = k4 * 32 + quad * 8 + j;
                tsq += qv * qv;
#pragma unroll
                for (int n = 0; n < 8; ++n) {
                    tp[n] += qv * posn[(size_t)(h * 8 + n) * 128 + d];
                    td[n] += qv * dirn[(size_t)(h * 8 + n) * 128 + d];
                }
            }
        }
        tsq += __shfl_xor(tsq, 16); tsq += __shfl_xor(tsq, 32);
        float dsv = 1.f / (1.f + __expf(-ds_in[0]));
#pragma unroll
        for (int n = 0; n < 8; ++n) {
            float a = tp[n]; a += __shfl_xor(a, 16); a += __shfl_xor(a, 32);
            float bb = td[n]; bb += __shfl_xor(bb, 16); bb += __shfl_xor(bb, 32);
            float dist2 = fmaxf(tsq - 2.f * a + pos_sq[h * 8 + n], 0.f);
            float proj = bb - pdv[h * 8 + n];
            float perp2 = fmaxf(dist2 - proj * proj, 0.f);
            float iv = iv2s2[h * 8 + n];
            float aff = (1.f - dsv) * __expf(-dist2 * iv) + dsv * __expf(-perp2 * iv);
            if (quad == 0) qas[wave][l15][n] = aff;
        }
    }

    {
        int n = tid >> 5, d = (tid & 31) * 4;
        f32x4 kv = {};
#pragma unroll
        for (int sc = 0; sc < 8; ++sc)
            kv += *(const f32x4*)(KVp + (((size_t)bh * 8 + n) * 8 + sc) * 128 + d);
        *(f32x4*)(KVs + tid * 4) = kv;
    }
    if (tid < 8) {
        float s = 0.f;
#pragma unroll
        for (int sc = 0; sc < 8; ++sc) s += S1p[((size_t)bh * 8 + tid) * 8 + sc];
        S1s[tid] = s;
    }

    const ushort_t* Kbase = Kg + (size_t)bh * 131072;
    const ushort_t* Vbase = Vtg + (size_t)bh * 131072;

#define STAGE(buf, kt_)                                                               \
    {                                                                                 \
        _Pragma("unroll") for (int i_ = 0; i_ < 4; ++i_) {                            \
            int off_ = tid * 16 + i_ * 4096;                                          \
            int kr_ = off_ >> 8, kp_ = (off_ >> 4) & 15;                              \
            async_copy16(Kbase + (size_t)(kt_)*8192 + kr_ * 128 + ((kp_ ^ (kr_ & 15)) << 3), \
                         (char*)(&Ks[buf][0]) + off_);                                \
            int vd_ = off_ >> 7, vp_ = (off_ >> 4) & 7;                               \
            async_copy16(Vbase + (size_t)vd_ * 1024 + (kt_)*64 + ((vp_ ^ (vd_ & 7)) << 3), \
                         (char*)(&Vt[buf][0]) + off_);                                \
        }                                                                             \
    }

    STAGE(0, 0);

    f32x4 o[8] = {};
    float l_i[4] = {};
    ushort_t* Pw = &Ps[wave][0];

    for (int kt = 0; kt < 16; ++kt) {
        __syncthreads();
        if (kt < 15) STAGE((kt + 1) & 1, kt + 1);
        const int cb = kt & 1;
        f32x4 sc[4] = {};
#pragma unroll
        for (int k4 = 0; k4 < 4; ++k4) {
#pragma unroll
            for (int t = 0; t < 4; ++t) {
                bf16x8 bk = *(const bf16x8*)((const char*)&Ks[cb][0] +
                                             ((t * 16 + l15) << 8) + (((k4 * 4 + quad) ^ l15) << 4));
                sc[t] = __builtin_amdgcn_mfma_f32_16x16x32_bf16(aq[k4], bk, sc[t], 0, 0, 0);
            }
        }
#pragma unroll
        for (int t = 0; t < 4; ++t) {
#pragma unroll
            for (int r = 0; r < 4; ++r) {
                float p = __expf(sc[t][r]);
                l_i[r] += p;
                Pw[(quad * 4 + r) * 72 + t * 16 + l15] = f2b(p);
            }
        }
        bf16x8 ap0 = *(const bf16x8*)((const char*)Pw + (l15 * 72 + quad * 8) * 2);
        bf16x8 ap1 = *(const bf16x8*)((const char*)Pw + (l15 * 72 + 32 + quad * 8) * 2);
#pragma unroll
        for (int j = 0; j < 8; ++j) {
            bf16x8 bv0 = *(const bf16x8*)((const char*)&Vt[cb][0] +
                                          ((j * 16 + l15) << 7) + (((quad) ^ (l15 & 7)) << 4));
            bf16x8 bv1 = *(const bf16x8*)((const char*)&Vt[cb][0] +
                                          ((j * 16 + l15) << 7) + (((4 + quad) ^ (l15 & 7)) << 4));
            o[j] = __builtin_amdgcn_mfma_f32_16x16x32_bf16(ap0, bv0, o[j], 0, 0, 0);
            o[j] = __builtin_amdgcn_mfma_f32_16x16x32_bf16(ap1, bv1, o[j], 0, 0, 0);
        }
    }
#undef STAGE
#pragma unroll
    for (int r = 0; r < 4; ++r) {
        float l = l_i[r];
        l += __shfl_xor(l, 1);
        l += __shfl_xor(l, 2);
        l += __shfl_xor(l, 4);
        l += __shfl_xor(l, 8);
        l_i[r] = l;
    }
    float gsa = 1.f / (1.f + __expf(-gstr[0]));
    float blend = fminf(0.05f, gsa * 0.1f);
    int b = bh >> 4;
#pragma unroll
    for (int r = 0; r < 4; ++r) {
        int q = qt * 64 + wave * 16 + quad * 4 + r;
        float qam[8], Z = 0.f;
#pragma unroll
        for (int n = 0; n < 8; ++n) {
            qam[n] = qas[wave][quad * 4 + r][n] * amp[h * 8 + n];
            Z += qam[n] * S1s[n];
        }
        float invZ = 1.f / (Z + 1e-8f);
        float invl = 1.f / l_i[r];
        ushort_t* outp = blended + ((size_t)(b * 1024 + q)) * 2048 + h * 128;
#pragma unroll
        for (int j = 0; j < 8; ++j) {
            int d = j * 16 + l15;
            float dg = 0.f;
#pragma unroll
            for (int n = 0; n < 8; ++n) dg += qam[n] * KVs[n * 128 + d];
            float v = (1.f - blend) * (o[j][r] * invl) + blend * (dg * invZ);
            outp[d] = f2b(v);
        }
    }
}

// ---------------------------------------------------------------------------
extern "C" void kernel_launch(void* const* d_in, const int* in_sizes, int n_in,
                              void* d_out, int out_size, void* d_ws, size_t ws_size,
                              hipStream_t stream) {
    const float* X = (const float*)d_in[0];
    const float* Wq = (const float*)d_in[1];
    const float* Wk = (const float*)d_in[2];
    const float* Wv = (const float*)d_in[3];
    const float* Wo = (const float*)d_in[4];
    const float* sp = (const float*)d_in[5];
    const float* sd = (const float*)d_in[6];
    const float* ls = (const float*)d_in[7];
    const float* la = (const float*)d_in[8];
    const float* dstr = (const float*)d_in[9];
    const float* gstr = (const float*)d_in[10];

    char* base = (char*)d_ws;
    ushort_t* WT4 = (ushort_t*)base;      base += 33554432;  // 4 x 2048^2 bf16
    ushort_t* Xbf = (ushort_t*)base;      base += 8388608;   // overlaid: blended
    ushort_t* blended = Xbf;                                 // Xbf dead after gemm_qkv
    ushort_t* Qbf = (ushort_t*)base;      base += 8388608;
    ushort_t* Kbf = (ushort_t*)base;      base += 8388608;
    ushort_t* Vbf = (ushort_t*)base;      base += 8388608;
    ushort_t* Vtb = (ushort_t*)base;      base += 8388608;
    float* kaw = (float*)base;            base += 1048576;
    float* posn = (float*)base;           base += 65536;
    float* dirn = (float*)base;           base += 65536;
    float* pos_sq = (float*)base;         base += 512;
    float* pdv = (float*)base;            base += 512;
    float* iv2s2 = (float*)base;          base += 512;
    float* ampw = (float*)base;           base += 512;
    float* S1p = (float*)base;            base += 8192;
    float* KVp = (float*)base;            base += 1048576;

    prep<<<dim3(64, 64, 5), 256, 0, stream>>>(X, Wq, Wk, Wv, Wo, sp, sd, ls, la,
                                              Xbf, WT4, posn, dirn, pos_sq, pdv, iv2s2, ampw);
    gemm_qkv<<<dim3(16, 48), 256, 0, stream>>>(Xbf, WT4, Qbf, Kbf, Vbf, Vtb);
    affinity_k<<<1024, 256, 0, stream>>>(Kbf, posn, dirn, pos_sq, pdv, iv2s2, dstr, kaw);
    kv_s1_part<<<dim3(32, 8), 128, 0, stream>>>(kaw, Vbf, KVp, S1p);
    flash_blend<<<dim3(16, 32), 256, 0, stream>>>(Qbf, Kbf, Vtb, posn, dirn, pos_sq, pdv,
                                                  iv2s2, dstr, ampw, S1p, KVp, gstr, blended);
    gemm_out<<<dim3(16, 32), 256, 0, stream>>>(blended, WT4 + 12582912, (float*)d_out);
}

// Round 6
// 345.923 us; speedup vs baseline: 1.0813x; 1.0813x over previous
//
#include <hip/hip_runtime.h>
#include <math.h>

typedef __attribute__((ext_vector_type(8))) short bf16x8;
typedef __attribute__((ext_vector_type(4))) float f32x4;
typedef unsigned short ushort_t;

#define SQRT_D 11.313708498984761f
#define INV_SQRT_D 0.08838834764831845f

__device__ __forceinline__ unsigned short f2b(float f) {
    unsigned u = __float_as_uint(f);
    unsigned r = (u + 0x7fffu + ((u >> 16) & 1u)) >> 16;
    return (unsigned short)r;
}
__device__ __forceinline__ float b2f(unsigned short h) {
    return __uint_as_float(((unsigned)h) << 16);
}

__device__ __forceinline__ void async_copy16(const void* g, void* l) {
    __builtin_amdgcn_global_load_lds((const __attribute__((address_space(1))) void*)g,
                                     (__attribute__((address_space(3))) void*)l, 16, 0, 0);
}

// ---------------------------------------------------------------------------
// prep: z<4 -> transpose W_z to bf16 WT4[z]; z==4 -> convert X to bf16; block
// (0,0,4) additionally runs splat_prep on its first 128 threads.
// ---------------------------------------------------------------------------
__global__ __launch_bounds__(256) void prep(
    const float* __restrict__ X, const float* __restrict__ W0,
    const float* __restrict__ W1, const float* __restrict__ W2,
    const float* __restrict__ W3, const float* __restrict__ sp,
    const float* __restrict__ sd, const float* __restrict__ ls,
    const float* __restrict__ la, ushort_t* __restrict__ Xbf,
    ushort_t* __restrict__ WT4, float* __restrict__ posn,
    float* __restrict__ dirn, float* __restrict__ pos_sq,
    float* __restrict__ pdv, float* __restrict__ iv2s2,
    float* __restrict__ amp) {
    __shared__ float t[32][33];
    const int z = blockIdx.z;
    if (z < 4) {
        const float* W = (z == 0) ? W0 : (z == 1) ? W1 : (z == 2) ? W2 : W3;
        ushort_t* WT = WT4 + (size_t)z * 4194304;
        int tx = threadIdx.x & 31, ty = threadIdx.x >> 5;
        int bn = blockIdx.x * 32, bk = blockIdx.y * 32;
#pragma unroll
        for (int i = 0; i < 4; ++i)
            t[ty + i * 8][tx] = W[(size_t)(bk + ty + i * 8) * 2048 + bn + tx];
        __syncthreads();
#pragma unroll
        for (int i = 0; i < 4; ++i)
            WT[(size_t)(bn + ty + i * 8) * 2048 + bk + tx] = f2b(t[tx][ty + i * 8]);
        return;
    }
    // convert X
    {
        int bi = blockIdx.y * 64 + blockIdx.x;
        int i = (bi * 256 + threadIdx.x) * 4;
        float4 v = *(const float4*)(X + i);
        ushort4 o;
        o.x = f2b(v.x); o.y = f2b(v.y); o.z = f2b(v.z); o.w = f2b(v.w);
        *(ushort4*)(Xbf + i) = o;
    }
    // splat prep (one block only)
    if (blockIdx.x == 0 && blockIdx.y == 0 && threadIdx.x < 128) {
        int i = threadIdx.x;
        const float* p = sp + (size_t)i * 128;
        const float* d = sd + (size_t)i * 128;
        float np_ = 0.f, nd_ = 0.f;
        for (int k = 0; k < 128; ++k) { np_ += p[k] * p[k]; nd_ += d[k] * d[k]; }
        np_ = sqrtf(np_); nd_ = sqrtf(nd_);
        const float sc = 3.394112549695428f;  // sqrt(128)*0.3
        float rp = sc / (np_ + 1e-12f);
        float rd = 1.f / (nd_ + 1e-12f);
        float psq = 0.f, pd_ = 0.f;
        for (int k = 0; k < 128; ++k) {
            float pn = p[k] * rp;
            float dn = d[k] * rd;
            posn[(size_t)i * 128 + k] = pn;
            dirn[(size_t)i * 128 + k] = dn;
            psq += pn * pn;
            pd_ += pn * dn;
        }
        pos_sq[i] = psq;
        pdv[i] = pd_;
        float s = expf(ls[i]);
        s = fminf(fmaxf(s, 0.3f), 1.2f);
        iv2s2[i] = 0.5f / (s * s);
        if ((i & 7) == 0) {
            int h = i >> 3;
            float mx = -INFINITY;
            for (int n = 0; n < 8; ++n) mx = fmaxf(mx, la[h * 8 + n]);
            float e[8]; float ssum = 0.f;
            for (int n = 0; n < 8; ++n) { e[n] = expf(la[h * 8 + n] - mx); ssum += e[n]; }
            for (int n = 0; n < 8; ++n) amp[h * 8 + n] = e[n] / ssum;
        }
    }
}

// LDS chunk swizzle (64 B rows, 4x16B chunks): phys = c ^ ((r + (r>>2)) & 3).

// ---------------------------------------------------------------------------
// gemm_qkv: fused Q/K/V projection, single-barrier double-buffered staging.
// grid (16,48); which = blockIdx.y>>4. Q scaled by 1/sqrt(D); V also [b,h,d,s].
// ---------------------------------------------------------------------------
__global__ __launch_bounds__(256) void gemm_qkv(const ushort_t* __restrict__ A,
                                                const ushort_t* __restrict__ WT4,
                                                ushort_t* __restrict__ Qb,
                                                ushort_t* __restrict__ Kb,
                                                ushort_t* __restrict__ Vb,
                                                ushort_t* __restrict__ Vt) {
    __shared__ ushort_t As[2][128 * 32];
    __shared__ ushort_t Bs[2][128 * 32];
    const int tid = threadIdx.x, lane = tid & 63, wave = tid >> 6;
    const int l15 = lane & 15, quad = lane >> 4;
    const int wm = (wave >> 1) * 64, wn = (wave & 1) * 64;
    const int bm = blockIdx.x * 128;
    const int by = blockIdx.y, which = by >> 4, bn = (by & 15) * 128;
    const ushort_t* BT = WT4 + (size_t)which * 4194304;
    f32x4 acc[4][4] = {};
    const int off0 = tid * 16;
    const int row0 = tid >> 2;
    const int c0 = (tid & 3) ^ ((row0 + (row0 >> 2)) & 3);
    const ushort_t* ga = A + (size_t)(bm + row0) * 2048 + c0 * 8;
    const ushort_t* gb = BT + (size_t)(bn + row0) * 2048 + c0 * 8;
    const int rsw = (l15 + (l15 >> 2)) & 3;
#define STAGEG(buf_, k_)                                                      \
    {                                                                         \
        async_copy16(ga + (k_), (char*)As[buf_] + off0);                      \
        async_copy16(ga + (size_t)64 * 2048 + (k_), (char*)As[buf_] + off0 + 4096); \
        async_copy16(gb + (k_), (char*)Bs[buf_] + off0);                      \
        async_copy16(gb + (size_t)64 * 2048 + (k_), (char*)Bs[buf_] + off0 + 4096); \
    }
    STAGEG(0, 0);
    for (int k0 = 0; k0 < 2048; k0 += 32) {
        __syncthreads();
        if (k0 < 2016) STAGEG(((k0 >> 5) + 1) & 1, k0 + 32);
        const int cb = (k0 >> 5) & 1;
        bf16x8 af[4], bfr[4];
#pragma unroll
        for (int i = 0; i < 4; ++i)
            af[i] = *(const bf16x8*)((const char*)As[cb] + (wm + i * 16 + l15) * 64 + ((quad ^ rsw) << 4));
#pragma unroll
        for (int j = 0; j < 4; ++j)
            bfr[j] = *(const bf16x8*)((const char*)Bs[cb] + (wn + j * 16 + l15) * 64 + ((quad ^ rsw) << 4));
#pragma unroll
        for (int i = 0; i < 4; ++i)
#pragma unroll
            for (int j = 0; j < 4; ++j)
                acc[i][j] = __builtin_amdgcn_mfma_f32_16x16x32_bf16(af[i], bfr[j], acc[i][j], 0, 0, 0);
    }
#undef STAGEG
    ushort_t* Cb = (which == 0) ? Qb : ((which == 1) ? Kb : Vb);
    const bool dot = (which == 2);
    const float oscale = (which == 0) ? INV_SQRT_D : 1.f;
#pragma unroll
    for (int i = 0; i < 4; ++i) {
#pragma unroll
        for (int j = 0; j < 4; ++j) {
            int m0 = bm + wm + i * 16 + quad * 4;
            int n = bn + wn + j * 16 + l15;
            int b = m0 >> 10, s0 = m0 & 1023, h = n >> 7, d = n & 127;
            ushort4 pack;
            unsigned short* pp = (unsigned short*)&pack;
#pragma unroll
            for (int r = 0; r < 4; ++r) {
                unsigned short bv = f2b(acc[i][j][r] * oscale);
                pp[r] = bv;
                Cb[((size_t)((b << 4) | h) * 1024 + (s0 + r)) * 128 + d] = bv;
            }
            if (dot) *(ushort4*)(Vt + ((size_t)((b << 4) | h) * 128 + d) * 1024 + s0) = pack;
        }
    }
}

// ---------------------------------------------------------------------------
// gemm_out: C(fp32) = A(bf16) @ BT^T. 128x64 tile, dbuf single-barrier.
// ---------------------------------------------------------------------------
__global__ __launch_bounds__(256) void gemm_out(const ushort_t* __restrict__ A,
                                                const ushort_t* __restrict__ BT,
                                                float* __restrict__ Cf) {
    __shared__ ushort_t As[2][128 * 32];
    __shared__ ushort_t Bs[2][64 * 32];
    const int tid = threadIdx.x, lane = tid & 63, wave = tid >> 6;
    const int l15 = lane & 15, quad = lane >> 4;
    const int wm = (wave >> 1) * 64, wn = (wave & 1) * 32;
    const int bm = blockIdx.x * 128, bn = blockIdx.y * 64;
    f32x4 acc[4][2] = {};
    const int off0 = tid * 16;
    const int row0 = tid >> 2;
    const int c0 = (tid & 3) ^ ((row0 + (row0 >> 2)) & 3);
    const ushort_t* ga = A + (size_t)(bm + row0) * 2048 + c0 * 8;
    const ushort_t* gb = BT + (size_t)(bn + row0) * 2048 + c0 * 8;
    const int rsw = (l15 + (l15 >> 2)) & 3;
#define STAGEO(buf_, k_)                                                      \
    {                                                                         \
        async_copy16(ga + (k_), (char*)As[buf_] + off0);                      \
        async_copy16(ga + (size_t)64 * 2048 + (k_), (char*)As[buf_] + off0 + 4096); \
        async_copy16(gb + (k_), (char*)Bs[buf_] + off0);                      \
    }
    STAGEO(0, 0);
    for (int k0 = 0; k0 < 2048; k0 += 32) {
        __syncthreads();
        if (k0 < 2016) STAGEO(((k0 >> 5) + 1) & 1, k0 + 32);
        const int cb = (k0 >> 5) & 1;
        bf16x8 af[4], bfr[2];
#pragma unroll
        for (int i = 0; i < 4; ++i)
            af[i] = *(const bf16x8*)((const char*)As[cb] + (wm + i * 16 + l15) * 64 + ((quad ^ rsw) << 4));
#pragma unroll
        for (int j = 0; j < 2; ++j)
            bfr[j] = *(const bf16x8*)((const char*)Bs[cb] + (wn + j * 16 + l15) * 64 + ((quad ^ rsw) << 4));
#pragma unroll
        for (int i = 0; i < 4; ++i)
#pragma unroll
            for (int j = 0; j < 2; ++j)
                acc[i][j] = __builtin_amdgcn_mfma_f32_16x16x32_bf16(af[i], bfr[j], acc[i][j], 0, 0, 0);
    }
#undef STAGEO
#pragma unroll
    for (int i = 0; i < 4; ++i)
#pragma unroll
        for (int j = 0; j < 2; ++j)
#pragma unroll
            for (int r = 0; r < 4; ++r) {
                int m = bm + wm + i * 16 + quad * 4 + r;
                int n = bn + wn + j * 16 + l15;
                Cf[(size_t)m * 2048 + n] = acc[i][j][r];
            }
}

// ---------------------------------------------------------------------------
// affinity_q: qa [B,NH,S,NS] from bf16 Q (prescaled by 1/sqrt(D) -> undo).
// ---------------------------------------------------------------------------
__global__ __launch_bounds__(256) void affinity_q(
    const ushort_t* __restrict__ Q,
    const float* __restrict__ posn, const float* __restrict__ dirn,
    const float* __restrict__ pos_sq, const float* __restrict__ pdv,
    const float* __restrict__ iv2s2, const float* __restrict__ ds_in,
    float* __restrict__ qa) {
    int gid = blockIdx.x * 256 + threadIdx.x;
    int n = gid & 7;
    int t = gid >> 3;  // 0..32767
    const ushort_t* T = Q + (size_t)t * 128;
    int h = (t >> 10) & 15;
    const float* P = posn + (size_t)(h * 8 + n) * 128;
    const float* Dr = dirn + (size_t)(h * 8 + n) * 128;
    float tsq = 0.f, tp = 0.f, td = 0.f;
#pragma unroll
    for (int d = 0; d < 128; d += 8) {
        uint4 raw = *(const uint4*)(T + d);
        float tv[8];
        tv[0] = __uint_as_float(raw.x << 16); tv[1] = __uint_as_float(raw.x & 0xffff0000u);
        tv[2] = __uint_as_float(raw.y << 16); tv[3] = __uint_as_float(raw.y & 0xffff0000u);
        tv[4] = __uint_as_float(raw.z << 16); tv[5] = __uint_as_float(raw.z & 0xffff0000u);
        tv[6] = __uint_as_float(raw.w << 16); tv[7] = __uint_as_float(raw.w & 0xffff0000u);
        float4 p0 = *(const float4*)(P + d), p1 = *(const float4*)(P + d + 4);
        float4 d0 = *(const float4*)(Dr + d), d1 = *(const float4*)(Dr + d + 4);
        tsq += tv[0]*tv[0]+tv[1]*tv[1]+tv[2]*tv[2]+tv[3]*tv[3]+tv[4]*tv[4]+tv[5]*tv[5]+tv[6]*tv[6]+tv[7]*tv[7];
        tp  += tv[0]*p0.x+tv[1]*p0.y+tv[2]*p0.z+tv[3]*p0.w+tv[4]*p1.x+tv[5]*p1.y+tv[6]*p1.z+tv[7]*p1.w;
        td  += tv[0]*d0.x+tv[1]*d0.y+tv[2]*d0.z+tv[3]*d0.w+tv[4]*d1.x+tv[5]*d1.y+tv[6]*d1.z+tv[7]*d1.w;
    }
    const float fs = SQRT_D;  // undo 1/sqrt(D) prescale on Q
    tsq *= fs * fs; tp *= fs; td *= fs;
    float dist2 = fmaxf(tsq - 2.f * tp + pos_sq[h * 8 + n], 0.f);
    float proj = td - pdv[h * 8 + n];
    float perp2 = fmaxf(dist2 - proj * proj, 0.f);
    float iv = iv2s2[h * 8 + n];
    float dsv = 1.f / (1.f + __expf(-ds_in[0]));
    float aff = (1.f - dsv) * __expf(-dist2 * iv) + dsv * __expf(-perp2 * iv);
    qa[(size_t)t * 8 + n] = aff;
}

// ---------------------------------------------------------------------------
// kv_s1_part: FUSED ka-affinity + partial KV/S1 over a 128-row S-chunk.
// grid (32 bh, 8 sc), 128 threads. Phase A: thread s computes ka[s][0..7]
// into LDS. Phase B: thread d accumulates sum_s ka[s][n]*V[s][d].
// ---------------------------------------------------------------------------
__global__ __launch_bounds__(128) void kv_s1_part(
    const ushort_t* __restrict__ K, const ushort_t* __restrict__ V,
    const float* __restrict__ posn, const float* __restrict__ dirn,
    const float* __restrict__ pos_sq, const float* __restrict__ pdv,
    const float* __restrict__ iv2s2, const float* __restrict__ ds_in,
    float* __restrict__ KVp, float* __restrict__ S1p) {
    __shared__ float kas[128][8];
    int bh = blockIdx.x, sc = blockIdx.y;
    int tid = threadIdx.x;
    int h = bh & 15;
    // Phase A: ka for token (bh, sc*128 + tid)
    {
        const ushort_t* T = K + ((size_t)bh * 1024 + sc * 128 + tid) * 128;
        float tsq = 0.f, tp[8] = {}, td[8] = {};
        for (int d = 0; d < 128; d += 4) {
            uint2 raw = *(const uint2*)(T + d);
            float t0 = __uint_as_float(raw.x << 16), t1 = __uint_as_float(raw.x & 0xffff0000u);
            float t2 = __uint_as_float(raw.y << 16), t3 = __uint_as_float(raw.y & 0xffff0000u);
            tsq += t0 * t0 + t1 * t1 + t2 * t2 + t3 * t3;
#pragma unroll
            for (int n = 0; n < 8; ++n) {
                const float* P = posn + (size_t)(h * 8 + n) * 128 + d;
                const float* Dr = dirn + (size_t)(h * 8 + n) * 128 + d;
                tp[n] += t0 * P[0] + t1 * P[1] + t2 * P[2] + t3 * P[3];
                td[n] += t0 * Dr[0] + t1 * Dr[1] + t2 * Dr[2] + t3 * Dr[3];
            }
        }
        float dsv = 1.f / (1.f + __expf(-ds_in[0]));
#pragma unroll
        for (int n = 0; n < 8; ++n) {
            float dist2 = fmaxf(tsq - 2.f * tp[n] + pos_sq[h * 8 + n], 0.f);
            float proj = td[n] - pdv[h * 8 + n];
            float perp2 = fmaxf(dist2 - proj * proj, 0.f);
            float iv = iv2s2[h * 8 + n];
            kas[tid][n] = (1.f - dsv) * __expf(-dist2 * iv) + dsv * __expf(-perp2 * iv);
        }
    }
    __syncthreads();
    // Phase B: KV accumulation (thread = d)
    int d = tid;
    const ushort_t* VB = V + ((size_t)bh * 1024 + sc * 128) * 128;
    float acc[8] = {};
#pragma unroll 4
    for (int s = 0; s < 128; ++s) {
        float vd = b2f(VB[(size_t)s * 128 + d]);
#pragma unroll
        for (int n = 0; n < 8; ++n) acc[n] += kas[s][n] * vd;
    }
#pragma unroll
    for (int n = 0; n < 8; ++n) KVp[(((size_t)bh * 8 + n) * 8 + sc) * 128 + d] = acc[n];
    // S1 partials
    __shared__ float s1p[128];
    {
        int n = d >> 4, chunk = d & 15;
        float p = 0.f;
        for (int s = chunk * 8; s < chunk * 8 + 8; ++s) p += kas[s][n];
        s1p[d] = p;
    }
    __syncthreads();
    if (d < 8) {
        float t = 0.f;
        for (int c = 0; c < 16; ++c) t += s1p[(d << 4) + c];
        S1p[((size_t)bh * 8 + d) * 8 + sc] = t;
    }
}

// ---------------------------------------------------------------------------
// flash_blend: grid (16 qt, 32 bh). 64 Q-rows/block, K-tile 64, dbuf swizzled
// staging, one barrier/iter, flat softmax (scores bounded ~|17|), qa from
// global. Lean registers (round-4 structure).
// ---------------------------------------------------------------------------
__global__ __launch_bounds__(256) void flash_blend(
    const ushort_t* __restrict__ Qg, const ushort_t* __restrict__ Kg,
    const ushort_t* __restrict__ Vtg,
    const float* __restrict__ qa, const float* __restrict__ amp,
    const float* __restrict__ S1p, const float* __restrict__ KVp,
    const float* __restrict__ gstr, ushort_t* __restrict__ blended) {
    __shared__ ushort_t Ks[2][64 * 128];   // [key][d], chunks swizzled ^(key&15)
    __shared__ ushort_t Vt[2][128 * 64];   // [d][key], chunks swizzled ^(d&7)
    __shared__ ushort_t Ps[4][16 * 72];    // wave-private P
    __shared__ float KVs[8 * 128];
    __shared__ float S1s[8];
    const int tid = threadIdx.x, lane = tid & 63, wave = tid >> 6;
    const int l15 = lane & 15, quad = lane >> 4;
    const int bh = blockIdx.y, qt = blockIdx.x;

    const ushort_t* Qrow = Qg + ((size_t)(bh * 1024 + qt * 64 + wave * 16 + l15)) * 128 + quad * 8;
    bf16x8 aq[4];
#pragma unroll
    for (int k4 = 0; k4 < 4; ++k4) aq[k4] = *(const bf16x8*)(Qrow + k4 * 32);

    {
        int n = tid >> 5, d = (tid & 31) * 4;
        f32x4 kv = {};
#pragma unroll
        for (int sc = 0; sc < 8; ++sc)
            kv += *(const f32x4*)(KVp + (((size_t)bh * 8 + n) * 8 + sc) * 128 + d);
        *(f32x4*)(KVs + tid * 4) = kv;
    }
    if (tid < 8) {
        float s = 0.f;
#pragma unroll
        for (int sc = 0; sc < 8; ++sc) s += S1p[((size_t)bh * 8 + tid) * 8 + sc];
        S1s[tid] = s;
    }

    const ushort_t* Kbase = Kg + (size_t)bh * 131072;
    const ushort_t* Vbase = Vtg + (size_t)bh * 131072;

#define STAGE(buf, kt_)                                                               \
    {                                                                                 \
        _Pragma("unroll") for (int i_ = 0; i_ < 4; ++i_) {                            \
            int off_ = tid * 16 + i_ * 4096;                                          \
            int kr_ = off_ >> 8, kp_ = (off_ >> 4) & 15;                              \
            async_copy16(Kbase + (size_t)(kt_)*8192 + kr_ * 128 + ((kp_ ^ (kr_ & 15)) << 3), \
                         (char*)(&Ks[buf][0]) + off_);                                \
            int vd_ = off_ >> 7, vp_ = (off_ >> 4) & 7;                               \
            async_copy16(Vbase + (size_t)vd_ * 1024 + (kt_)*64 + ((vp_ ^ (vd_ & 7)) << 3), \
                         (char*)(&Vt[buf][0]) + off_);                                \
        }                                                                             \
    }

    STAGE(0, 0);

    f32x4 o[8] = {};
    float l_i[4] = {};
    ushort_t* Pw = &Ps[wave][0];

    for (int kt = 0; kt < 16; ++kt) {
        __syncthreads();
        if (kt < 15) STAGE((kt + 1) & 1, kt + 1);
        const int cb = kt & 1;
        f32x4 sc[4] = {};
#pragma unroll
        for (int k4 = 0; k4 < 4; ++k4) {
#pragma unroll
            for (int t = 0; t < 4; ++t) {
                bf16x8 bk = *(const bf16x8*)((const char*)&Ks[cb][0] +
                                             ((t * 16 + l15) << 8) + (((k4 * 4 + quad) ^ l15) << 4));
                sc[t] = __builtin_amdgcn_mfma_f32_16x16x32_bf16(aq[k4], bk, sc[t], 0, 0, 0);
            }
        }
#pragma unroll
        for (int t = 0; t < 4; ++t) {
#pragma unroll
            for (int r = 0; r < 4; ++r) {
                float p = __expf(sc[t][r]);
                l_i[r] += p;
                Pw[(quad * 4 + r) * 72 + t * 16 + l15] = f2b(p);
            }
        }
        bf16x8 ap0 = *(const bf16x8*)((const char*)Pw + (l15 * 72 + quad * 8) * 2);
        bf16x8 ap1 = *(const bf16x8*)((const char*)Pw + (l15 * 72 + 32 + quad * 8) * 2);
#pragma unroll
        for (int j = 0; j < 8; ++j) {
            bf16x8 bv0 = *(const bf16x8*)((const char*)&Vt[cb][0] +
                                          ((j * 16 + l15) << 7) + (((quad) ^ (l15 & 7)) << 4));
            bf16x8 bv1 = *(const bf16x8*)((const char*)&Vt[cb][0] +
                                          ((j * 16 + l15) << 7) + (((4 + quad) ^ (l15 & 7)) << 4));
            o[j] = __builtin_amdgcn_mfma_f32_16x16x32_bf16(ap0, bv0, o[j], 0, 0, 0);
            o[j] = __builtin_amdgcn_mfma_f32_16x16x32_bf16(ap1, bv1, o[j], 0, 0, 0);
        }
    }
#undef STAGE
#pragma unroll
    for (int r = 0; r < 4; ++r) {
        float l = l_i[r];
        l += __shfl_xor(l, 1);
        l += __shfl_xor(l, 2);
        l += __shfl_xor(l, 4);
        l += __shfl_xor(l, 8);
        l_i[r] = l;
    }
    float gsa = 1.f / (1.f + __expf(-gstr[0]));
    float blend = fminf(0.05f, gsa * 0.1f);
    int b = bh >> 4, h = bh & 15;
#pragma unroll
    for (int r = 0; r < 4; ++r) {
        int q = qt * 64 + wave * 16 + quad * 4 + r;
        const float* qaRow = qa + ((size_t)bh * 1024 + q) * 8;
        float qam[8], Z = 0.f;
#pragma unroll
        for (int n = 0; n < 8; ++n) {
            qam[n] = qaRow[n] * amp[h * 8 + n];
            Z += qam[n] * S1s[n];
        }
        float invZ = 1.f / (Z + 1e-8f);
        float invl = 1.f / l_i[r];
        ushort_t* outp = blended + ((size_t)(b * 1024 + q)) * 2048 + h * 128;
#pragma unroll
        for (int j = 0; j < 8; ++j) {
            int d = j * 16 + l15;
            float dg = 0.f;
#pragma unroll
            for (int n = 0; n < 8; ++n) dg += qam[n] * KVs[n * 128 + d];
            float v = (1.f - blend) * (o[j][r] * invl) + blend * (dg * invZ);
            outp[d] = f2b(v);
        }
    }
}

// ---------------------------------------------------------------------------
extern "C" void kernel_launch(void* const* d_in, const int* in_sizes, int n_in,
                              void* d_out, int out_size, void* d_ws, size_t ws_size,
                              hipStream_t stream) {
    const float* X = (const float*)d_in[0];
    const float* Wq = (const float*)d_in[1];
    const float* Wk = (const float*)d_in[2];
    const float* Wv = (const float*)d_in[3];
    const float* Wo = (const float*)d_in[4];
    const float* sp = (const float*)d_in[5];
    const float* sd = (const float*)d_in[6];
    const float* ls = (const float*)d_in[7];
    const float* la = (const float*)d_in[8];
    const float* dstr = (const float*)d_in[9];
    const float* gstr = (const float*)d_in[10];

    char* base = (char*)d_ws;
    ushort_t* WT4 = (ushort_t*)base;      base += 33554432;  // 4 x 2048^2 bf16
    ushort_t* Xbf = (ushort_t*)base;      base += 8388608;   // overlaid: blended
    ushort_t* blended = Xbf;                                 // Xbf dead after gemm_qkv
    ushort_t* Qbf = (ushort_t*)base;      base += 8388608;
    ushort_t* Kbf = (ushort_t*)base;      base += 8388608;
    ushort_t* Vbf = (ushort_t*)base;      base += 8388608;
    ushort_t* Vtb = (ushort_t*)base;      base += 8388608;
    float* qaw = (float*)base;            base += 1048576;
    float* posn = (float*)base;           base += 65536;
    float* dirn = (float*)base;           base += 65536;
    float* pos_sq = (float*)base;         base += 512;
    float* pdv = (float*)base;            base += 512;
    float* iv2s2 = (float*)base;          base += 512;
    float* ampw = (float*)base;           base += 512;
    float* S1p = (float*)base;            base += 8192;
    float* KVp = (float*)base;            base += 1048576;

    prep<<<dim3(64, 64, 5), 256, 0, stream>>>(X, Wq, Wk, Wv, Wo, sp, sd, ls, la,
                                              Xbf, WT4, posn, dirn, pos_sq, pdv, iv2s2, ampw);
    gemm_qkv<<<dim3(16, 48), 256, 0, stream>>>(Xbf, WT4, Qbf, Kbf, Vbf, Vtb);
    affinity_q<<<1024, 256, 0, stream>>>(Qbf, posn, dirn, pos_sq, pdv, iv2s2, dstr, qaw);
    kv_s1_part<<<dim3(32, 8), 128, 0, stream>>>(Kbf, Vbf, posn, dirn, pos_sq, pdv, iv2s2,
                                                dstr, KVp, S1p);
    flash_blend<<<dim3(16, 32), 256, 0, stream>>>(Qbf, Kbf, Vtb, qaw, ampw, S1p, KVp,
                                                  gstr, blended);
    gemm_out<<<dim3(16, 32), 256, 0, stream>>>(blended, WT4 + 12582912, (float*)d_out);
}

// Round 7
// 333.334 us; speedup vs baseline: 1.1222x; 1.0378x over previous
//
#include <hip/hip_runtime.h>
#include <math.h>

typedef __attribute__((ext_vector_type(8))) short bf16x8;
typedef __attribute__((ext_vector_type(4))) float f32x4;
typedef unsigned short ushort_t;

#define SQRT_D 11.313708498984761f
#define INV_SQRT_D 0.08838834764831845f

__device__ __forceinline__ unsigned short f2b(float f) {
    unsigned u = __float_as_uint(f);
    unsigned r = (u + 0x7fffu + ((u >> 16) & 1u)) >> 16;
    return (unsigned short)r;
}
__device__ __forceinline__ float b2f(unsigned short h) {
    return __uint_as_float(((unsigned)h) << 16);
}

__device__ __forceinline__ void async_copy16(const void* g, void* l) {
    __builtin_amdgcn_global_load_lds((const __attribute__((address_space(1))) void*)g,
                                     (__attribute__((address_space(3))) void*)l, 16, 0, 0);
}

// ---------------------------------------------------------------------------
// prep: z<4 -> transpose W_z to bf16 WT4[z]; z==4 -> convert X to bf16; block
// (0,0,4) additionally runs splat_prep on its first 128 threads.
// ---------------------------------------------------------------------------
__global__ __launch_bounds__(256) void prep(
    const float* __restrict__ X, const float* __restrict__ W0,
    const float* __restrict__ W1, const float* __restrict__ W2,
    const float* __restrict__ W3, const float* __restrict__ sp,
    const float* __restrict__ sd, const float* __restrict__ ls,
    const float* __restrict__ la, ushort_t* __restrict__ Xbf,
    ushort_t* __restrict__ WT4, float* __restrict__ posn,
    float* __restrict__ dirn, float* __restrict__ pos_sq,
    float* __restrict__ pdv, float* __restrict__ iv2s2,
    float* __restrict__ amp) {
    __shared__ float t[32][33];
    const int z = blockIdx.z;
    if (z < 4) {
        const float* W = (z == 0) ? W0 : (z == 1) ? W1 : (z == 2) ? W2 : W3;
        ushort_t* WT = WT4 + (size_t)z * 4194304;
        int tx = threadIdx.x & 31, ty = threadIdx.x >> 5;
        int bn = blockIdx.x * 32, bk = blockIdx.y * 32;
#pragma unroll
        for (int i = 0; i < 4; ++i)
            t[ty + i * 8][tx] = W[(size_t)(bk + ty + i * 8) * 2048 + bn + tx];
        __syncthreads();
#pragma unroll
        for (int i = 0; i < 4; ++i)
            WT[(size_t)(bn + ty + i * 8) * 2048 + bk + tx] = f2b(t[tx][ty + i * 8]);
        return;
    }
    // convert X
    {
        int bi = blockIdx.y * 64 + blockIdx.x;
        int i = (bi * 256 + threadIdx.x) * 4;
        float4 v = *(const float4*)(X + i);
        ushort4 o;
        o.x = f2b(v.x); o.y = f2b(v.y); o.z = f2b(v.z); o.w = f2b(v.w);
        *(ushort4*)(Xbf + i) = o;
    }
    // splat prep (one block only)
    if (blockIdx.x == 0 && blockIdx.y == 0 && threadIdx.x < 128) {
        int i = threadIdx.x;
        const float* p = sp + (size_t)i * 128;
        const float* d = sd + (size_t)i * 128;
        float np_ = 0.f, nd_ = 0.f;
        for (int k = 0; k < 128; ++k) { np_ += p[k] * p[k]; nd_ += d[k] * d[k]; }
        np_ = sqrtf(np_); nd_ = sqrtf(nd_);
        const float sc = 3.394112549695428f;  // sqrt(128)*0.3
        float rp = sc / (np_ + 1e-12f);
        float rd = 1.f / (nd_ + 1e-12f);
        float psq = 0.f, pd_ = 0.f;
        for (int k = 0; k < 128; ++k) {
            float pn = p[k] * rp;
            float dn = d[k] * rd;
            posn[(size_t)i * 128 + k] = pn;
            dirn[(size_t)i * 128 + k] = dn;
            psq += pn * pn;
            pd_ += pn * dn;
        }
        pos_sq[i] = psq;
        pdv[i] = pd_;
        float s = expf(ls[i]);
        s = fminf(fmaxf(s, 0.3f), 1.2f);
        iv2s2[i] = 0.5f / (s * s);
        if ((i & 7) == 0) {
            int h = i >> 3;
            float mx = -INFINITY;
            for (int n = 0; n < 8; ++n) mx = fmaxf(mx, la[h * 8 + n]);
            float e[8]; float ssum = 0.f;
            for (int n = 0; n < 8; ++n) { e[n] = expf(la[h * 8 + n] - mx); ssum += e[n]; }
            for (int n = 0; n < 8; ++n) amp[h * 8 + n] = e[n] / ssum;
        }
    }
}

// LDS chunk swizzle (64 B rows, 4x16B chunks): phys = c ^ ((r + (r>>2)) & 3).

// ---------------------------------------------------------------------------
// gemm_qkv: fused Q/K/V projection. K-loop unrolled x2 so the double-buffer
// index is compile-time (dbuf latency-hiding WITHOUT dynamic-index VALU tax).
// grid (16,48); which = blockIdx.y>>4. Q scaled by 1/sqrt(D); V also [b,h,d,s].
// ---------------------------------------------------------------------------
__global__ __launch_bounds__(256) void gemm_qkv(const ushort_t* __restrict__ A,
                                                const ushort_t* __restrict__ WT4,
                                                ushort_t* __restrict__ Qb,
                                                ushort_t* __restrict__ Kb,
                                                ushort_t* __restrict__ Vb,
                                                ushort_t* __restrict__ Vt) {
    __shared__ ushort_t As0[128 * 32], As1[128 * 32];
    __shared__ ushort_t Bs0[128 * 32], Bs1[128 * 32];
    const int tid = threadIdx.x, lane = tid & 63, wave = tid >> 6;
    const int l15 = lane & 15, quad = lane >> 4;
    const int wm = (wave >> 1) * 64, wn = (wave & 1) * 64;
    const int bm = blockIdx.x * 128;
    const int by = blockIdx.y, which = by >> 4, bn = (by & 15) * 128;
    const ushort_t* BT = WT4 + (size_t)which * 4194304;
    f32x4 acc[4][4] = {};
    const int off0 = tid * 16;
    const int row0 = tid >> 2;
    const int c0 = (tid & 3) ^ ((row0 + (row0 >> 2)) & 3);
    const ushort_t* ga = A + (size_t)(bm + row0) * 2048 + c0 * 8;
    const ushort_t* gb = BT + (size_t)(bn + row0) * 2048 + c0 * 8;
    const int rsw = (l15 + (l15 >> 2)) & 3;
#define STAGEG(ABUF, BBUF, k_)                                                 \
    {                                                                          \
        async_copy16(ga + (k_), (char*)(ABUF) + off0);                         \
        async_copy16(ga + (size_t)64 * 2048 + (k_), (char*)(ABUF) + off0 + 4096); \
        async_copy16(gb + (k_), (char*)(BBUF) + off0);                         \
        async_copy16(gb + (size_t)64 * 2048 + (k_), (char*)(BBUF) + off0 + 4096); \
    }
#define COMPUTEG(ABUF, BBUF)                                                   \
    {                                                                          \
        bf16x8 af[4], bfr[4];                                                  \
        _Pragma("unroll") for (int i = 0; i < 4; ++i)                          \
            af[i] = *(const bf16x8*)((const char*)(ABUF) + (wm + i * 16 + l15) * 64 + ((quad ^ rsw) << 4)); \
        _Pragma("unroll") for (int j = 0; j < 4; ++j)                          \
            bfr[j] = *(const bf16x8*)((const char*)(BBUF) + (wn + j * 16 + l15) * 64 + ((quad ^ rsw) << 4)); \
        _Pragma("unroll") for (int i = 0; i < 4; ++i)                          \
            _Pragma("unroll") for (int j = 0; j < 4; ++j)                      \
                acc[i][j] = __builtin_amdgcn_mfma_f32_16x16x32_bf16(af[i], bfr[j], acc[i][j], 0, 0, 0); \
    }
    STAGEG(As0, Bs0, 0);
    for (int k0 = 0; k0 < 2048; k0 += 64) {
        __syncthreads();
        STAGEG(As1, Bs1, k0 + 32);
        COMPUTEG(As0, Bs0);
        __syncthreads();
        if (k0 + 64 < 2048) STAGEG(As0, Bs0, k0 + 64);
        COMPUTEG(As1, Bs1);
    }
#undef STAGEG
#undef COMPUTEG
    ushort_t* Cb = (which == 0) ? Qb : ((which == 1) ? Kb : Vb);
    const bool dot = (which == 2);
    const float oscale = (which == 0) ? INV_SQRT_D : 1.f;
#pragma unroll
    for (int i = 0; i < 4; ++i) {
#pragma unroll
        for (int j = 0; j < 4; ++j) {
            int m0 = bm + wm + i * 16 + quad * 4;
            int n = bn + wn + j * 16 + l15;
            int b = m0 >> 10, s0 = m0 & 1023, h = n >> 7, d = n & 127;
            ushort4 pack;
            unsigned short* pp = (unsigned short*)&pack;
#pragma unroll
            for (int r = 0; r < 4; ++r) {
                unsigned short bv = f2b(acc[i][j][r] * oscale);
                pp[r] = bv;
                Cb[((size_t)((b << 4) | h) * 1024 + (s0 + r)) * 128 + d] = bv;
            }
            if (dot) *(ushort4*)(Vt + ((size_t)((b << 4) | h) * 128 + d) * 1024 + s0) = pack;
        }
    }
}

// ---------------------------------------------------------------------------
// gemm_out: C(fp32) = A(bf16) @ BT^T. 128x64 tile, unrolled-x2 dbuf.
// ---------------------------------------------------------------------------
__global__ __launch_bounds__(256) void gemm_out(const ushort_t* __restrict__ A,
                                                const ushort_t* __restrict__ BT,
                                                float* __restrict__ Cf) {
    __shared__ ushort_t As0[128 * 32], As1[128 * 32];
    __shared__ ushort_t Bs0[64 * 32], Bs1[64 * 32];
    const int tid = threadIdx.x, lane = tid & 63, wave = tid >> 6;
    const int l15 = lane & 15, quad = lane >> 4;
    const int wm = (wave >> 1) * 64, wn = (wave & 1) * 32;
    const int bm = blockIdx.x * 128, bn = blockIdx.y * 64;
    f32x4 acc[4][2] = {};
    const int off0 = tid * 16;
    const int row0 = tid >> 2;
    const int c0 = (tid & 3) ^ ((row0 + (row0 >> 2)) & 3);
    const ushort_t* ga = A + (size_t)(bm + row0) * 2048 + c0 * 8;
    const ushort_t* gb = BT + (size_t)(bn + row0) * 2048 + c0 * 8;
    const int rsw = (l15 + (l15 >> 2)) & 3;
#define STAGEO(ABUF, BBUF, k_)                                                 \
    {                                                                          \
        async_copy16(ga + (k_), (char*)(ABUF) + off0);                         \
        async_copy16(ga + (size_t)64 * 2048 + (k_), (char*)(ABUF) + off0 + 4096); \
        async_copy16(gb + (k_), (char*)(BBUF) + off0);                         \
    }
#define COMPUTEO(ABUF, BBUF)                                                   \
    {                                                                          \
        bf16x8 af[4], bfr[2];                                                  \
        _Pragma("unroll") for (int i = 0; i < 4; ++i)                          \
            af[i] = *(const bf16x8*)((const char*)(ABUF) + (wm + i * 16 + l15) * 64 + ((quad ^ rsw) << 4)); \
        _Pragma("unroll") for (int j = 0; j < 2; ++j)                          \
            bfr[j] = *(const bf16x8*)((const char*)(BBUF) + (wn + j * 16 + l15) * 64 + ((quad ^ rsw) << 4)); \
        _Pragma("unroll") for (int i = 0; i < 4; ++i)                          \
            _Pragma("unroll") for (int j = 0; j < 2; ++j)                      \
                acc[i][j] = __builtin_amdgcn_mfma_f32_16x16x32_bf16(af[i], bfr[j], acc[i][j], 0, 0, 0); \
    }
    STAGEO(As0, Bs0, 0);
    for (int k0 = 0; k0 < 2048; k0 += 64) {
        __syncthreads();
        STAGEO(As1, Bs1, k0 + 32);
        COMPUTEO(As0, Bs0);
        __syncthreads();
        if (k0 + 64 < 2048) STAGEO(As0, Bs0, k0 + 64);
        COMPUTEO(As1, Bs1);
    }
#undef STAGEO
#undef COMPUTEO
#pragma unroll
    for (int i = 0; i < 4; ++i)
#pragma unroll
        for (int j = 0; j < 2; ++j)
#pragma unroll
            for (int r = 0; r < 4; ++r) {
                int m = bm + wm + i * 16 + quad * 4 + r;
                int n = bn + wn + j * 16 + l15;
                Cf[(size_t)m * 2048 + n] = acc[i][j][r];
            }
}

// ---------------------------------------------------------------------------
// affinity_q: qa [B,NH,S,NS] from bf16 Q (prescaled by 1/sqrt(D) -> undo).
// ---------------------------------------------------------------------------
__global__ __launch_bounds__(256) void affinity_q(
    const ushort_t* __restrict__ Q,
    const float* __restrict__ posn, const float* __restrict__ dirn,
    const float* __restrict__ pos_sq, const float* __restrict__ pdv,
    const float* __restrict__ iv2s2, const float* __restrict__ ds_in,
    float* __restrict__ qa) {
    int gid = blockIdx.x * 256 + threadIdx.x;
    int n = gid & 7;
    int t = gid >> 3;  // 0..32767
    const ushort_t* T = Q + (size_t)t * 128;
    int h = (t >> 10) & 15;
    const float* P = posn + (size_t)(h * 8 + n) * 128;
    const float* Dr = dirn + (size_t)(h * 8 + n) * 128;
    float tsq = 0.f, tp = 0.f, td = 0.f;
#pragma unroll
    for (int d = 0; d < 128; d += 8) {
        uint4 raw = *(const uint4*)(T + d);
        float tv[8];
        tv[0] = __uint_as_float(raw.x << 16); tv[1] = __uint_as_float(raw.x & 0xffff0000u);
        tv[2] = __uint_as_float(raw.y << 16); tv[3] = __uint_as_float(raw.y & 0xffff0000u);
        tv[4] = __uint_as_float(raw.z << 16); tv[5] = __uint_as_float(raw.z & 0xffff0000u);
        tv[6] = __uint_as_float(raw.w << 16); tv[7] = __uint_as_float(raw.w & 0xffff0000u);
        float4 p0 = *(const float4*)(P + d), p1 = *(const float4*)(P + d + 4);
        float4 d0 = *(const float4*)(Dr + d), d1 = *(const float4*)(Dr + d + 4);
        tsq += tv[0]*tv[0]+tv[1]*tv[1]+tv[2]*tv[2]+tv[3]*tv[3]+tv[4]*tv[4]+tv[5]*tv[5]+tv[6]*tv[6]+tv[7]*tv[7];
        tp  += tv[0]*p0.x+tv[1]*p0.y+tv[2]*p0.z+tv[3]*p0.w+tv[4]*p1.x+tv[5]*p1.y+tv[6]*p1.z+tv[7]*p1.w;
        td  += tv[0]*d0.x+tv[1]*d0.y+tv[2]*d0.z+tv[3]*d0.w+tv[4]*d1.x+tv[5]*d1.y+tv[6]*d1.z+tv[7]*d1.w;
    }
    const float fs = SQRT_D;  // undo 1/sqrt(D) prescale on Q
    tsq *= fs * fs; tp *= fs; td *= fs;
    float dist2 = fmaxf(tsq - 2.f * tp + pos_sq[h * 8 + n], 0.f);
    float proj = td - pdv[h * 8 + n];
    float perp2 = fmaxf(dist2 - proj * proj, 0.f);
    float iv = iv2s2[h * 8 + n];
    float dsv = 1.f / (1.f + __expf(-ds_in[0]));
    float aff = (1.f - dsv) * __expf(-dist2 * iv) + dsv * __expf(-perp2 * iv);
    qa[(size_t)t * 8 + n] = aff;
}

// ---------------------------------------------------------------------------
// kv_s1_part: FUSED ka-affinity + partial KV/S1 over a 64-row S-chunk.
// grid (32 bh, 16 sc), 128 threads. Phase A (tid<64): ka for token into LDS.
// Phase B (all): thread d accumulates sum_s ka[s][n]*V[s][d] over 64 rows.
// ---------------------------------------------------------------------------
__global__ __launch_bounds__(128) void kv_s1_part(
    const ushort_t* __restrict__ K, const ushort_t* __restrict__ V,
    const float* __restrict__ posn, const float* __restrict__ dirn,
    const float* __restrict__ pos_sq, const float* __restrict__ pdv,
    const float* __restrict__ iv2s2, const float* __restrict__ ds_in,
    float* __restrict__ KVp, float* __restrict__ S1p) {
    __shared__ float kas[64][8];
    int bh = blockIdx.x, sc = blockIdx.y;
    int tid = threadIdx.x;
    int h = bh & 15;
    // Phase A: ka for token (bh, sc*64 + tid), tid < 64
    if (tid < 64) {
        const ushort_t* T = K + ((size_t)bh * 1024 + sc * 64 + tid) * 128;
        float tsq = 0.f, tp[8] = {}, td[8] = {};
        for (int d = 0; d < 128; d += 4) {
            uint2 raw = *(const uint2*)(T + d);
            float t0 = __uint_as_float(raw.x << 16), t1 = __uint_as_float(raw.x & 0xffff0000u);
            float t2 = __uint_as_float(raw.y << 16), t3 = __uint_as_float(raw.y & 0xffff0000u);
            tsq += t0 * t0 + t1 * t1 + t2 * t2 + t3 * t3;
#pragma unroll
            for (int n = 0; n < 8; ++n) {
                const float* P = posn + (size_t)(h * 8 + n) * 128 + d;
                const float* Dr = dirn + (size_t)(h * 8 + n) * 128 + d;
                tp[n] += t0 * P[0] + t1 * P[1] + t2 * P[2] + t3 * P[3];
                td[n] += t0 * Dr[0] + t1 * Dr[1] + t2 * Dr[2] + t3 * Dr[3];
            }
        }
        float dsv = 1.f / (1.f + __expf(-ds_in[0]));
#pragma unroll
        for (int n = 0; n < 8; ++n) {
            float dist2 = fmaxf(tsq - 2.f * tp[n] + pos_sq[h * 8 + n], 0.f);
            float proj = td[n] - pdv[h * 8 + n];
            float perp2 = fmaxf(dist2 - proj * proj, 0.f);
            float iv = iv2s2[h * 8 + n];
            kas[tid][n] = (1.f - dsv) * __expf(-dist2 * iv) + dsv * __expf(-perp2 * iv);
        }
    }
    __syncthreads();
    // Phase B: KV accumulation (thread = d)
    int d = tid;
    const ushort_t* VB = V + ((size_t)bh * 1024 + sc * 64) * 128;
    float acc[8] = {};
#pragma unroll 4
    for (int s = 0; s < 64; ++s) {
        float vd = b2f(VB[(size_t)s * 128 + d]);
#pragma unroll
        for (int n = 0; n < 8; ++n) acc[n] += kas[s][n] * vd;
    }
#pragma unroll
    for (int n = 0; n < 8; ++n) KVp[(((size_t)bh * 8 + n) * 16 + sc) * 128 + d] = acc[n];
    // S1 partials
    __shared__ float s1p[128];
    {
        int n = d >> 4, chunk = d & 15;
        float p = 0.f;
        for (int s = chunk * 4; s < chunk * 4 + 4; ++s) p += kas[s][n];
        s1p[d] = p;
    }
    __syncthreads();
    if (d < 8) {
        float t = 0.f;
        for (int c = 0; c < 16; ++c) t += s1p[(d << 4) + c];
        S1p[((size_t)bh * 8 + d) * 16 + sc] = t;
    }
}

// ---------------------------------------------------------------------------
// flash_blend: grid (16 qt, 32 bh). 64 Q-rows/block, K-tile 64, unrolled-x2
// dbuf swizzled staging, one barrier/iter, flat softmax, qa from global.
// ---------------------------------------------------------------------------
__global__ __launch_bounds__(256) void flash_blend(
    const ushort_t* __restrict__ Qg, const ushort_t* __restrict__ Kg,
    const ushort_t* __restrict__ Vtg,
    const float* __restrict__ qa, const float* __restrict__ amp,
    const float* __restrict__ S1p, const float* __restrict__ KVp,
    const float* __restrict__ gstr, ushort_t* __restrict__ blended) {
    __shared__ ushort_t Ks0[64 * 128], Ks1[64 * 128];  // [key][d], swizzled ^(key&15)
    __shared__ ushort_t Vt0[128 * 64], Vt1[128 * 64];  // [d][key], swizzled ^(d&7)
    __shared__ ushort_t Ps[4][16 * 72];                // wave-private P
    __shared__ float KVs[8 * 128];
    __shared__ float S1s[8];
    const int tid = threadIdx.x, lane = tid & 63, wave = tid >> 6;
    const int l15 = lane & 15, quad = lane >> 4;
    const int bh = blockIdx.y, qt = blockIdx.x;

    const ushort_t* Qrow = Qg + ((size_t)(bh * 1024 + qt * 64 + wave * 16 + l15)) * 128 + quad * 8;
    bf16x8 aq[4];
#pragma unroll
    for (int k4 = 0; k4 < 4; ++k4) aq[k4] = *(const bf16x8*)(Qrow + k4 * 32);

    {
        int n = tid >> 5, d = (tid & 31) * 4;
        f32x4 kv = {};
#pragma unroll
        for (int sc = 0; sc < 16; ++sc)
            kv += *(const f32x4*)(KVp + (((size_t)bh * 8 + n) * 16 + sc) * 128 + d);
        *(f32x4*)(KVs + tid * 4) = kv;
    }
    if (tid < 8) {
        float s = 0.f;
#pragma unroll
        for (int sc = 0; sc < 16; ++sc) s += S1p[((size_t)bh * 8 + tid) * 16 + sc];
        S1s[tid] = s;
    }

    const ushort_t* Kbase = Kg + (size_t)bh * 131072;
    const ushort_t* Vbase = Vtg + (size_t)bh * 131072;

#define STAGE(KBUF, VBUF, kt_)                                                        \
    {                                                                                 \
        _Pragma("unroll") for (int i_ = 0; i_ < 4; ++i_) {                            \
            int off_ = tid * 16 + i_ * 4096;                                          \
            int kr_ = off_ >> 8, kp_ = (off_ >> 4) & 15;                              \
            async_copy16(Kbase + (size_t)(kt_)*8192 + kr_ * 128 + ((kp_ ^ (kr_ & 15)) << 3), \
                         (char*)(KBUF) + off_);                                       \
            int vd_ = off_ >> 7, vp_ = (off_ >> 4) & 7;                               \
            async_copy16(Vbase + (size_t)vd_ * 1024 + (kt_)*64 + ((vp_ ^ (vd_ & 7)) << 3), \
                         (char*)(VBUF) + off_);                                       \
        }                                                                             \
    }
#define FLASH_STEP(KBUF, VBUF)                                                        \
    {                                                                                 \
        f32x4 sc[4] = {};                                                             \
        _Pragma("unroll") for (int k4 = 0; k4 < 4; ++k4) {                            \
            _Pragma("unroll") for (int t = 0; t < 4; ++t) {                           \
                bf16x8 bk = *(const bf16x8*)((const char*)(KBUF) +                    \
                                             ((t * 16 + l15) << 8) + (((k4 * 4 + quad) ^ l15) << 4)); \
                sc[t] = __builtin_amdgcn_mfma_f32_16x16x32_bf16(aq[k4], bk, sc[t], 0, 0, 0); \
            }                                                                         \
        }                                                                             \
        _Pragma("unroll") for (int t = 0; t < 4; ++t) {                               \
            _Pragma("unroll") for (int r = 0; r < 4; ++r) {                           \
                float p = __expf(sc[t][r]);                                           \
                l_i[r] += p;                                                          \
                Pw[(quad * 4 + r) * 72 + t * 16 + l15] = f2b(p);                      \
            }                                                                         \
        }                                                                             \
        bf16x8 ap0 = *(const bf16x8*)((const char*)Pw + (l15 * 72 + quad * 8) * 2);   \
        bf16x8 ap1 = *(const bf16x8*)((const char*)Pw + (l15 * 72 + 32 + quad * 8) * 2); \
        _Pragma("unroll") for (int j = 0; j < 8; ++j) {                               \
            bf16x8 bv0 = *(const bf16x8*)((const char*)(VBUF) +                       \
                                          ((j * 16 + l15) << 7) + (((quad) ^ (l15 & 7)) << 4)); \
            bf16x8 bv1 = *(const bf16x8*)((const char*)(VBUF) +                       \
                                          ((j * 16 + l15) << 7) + (((4 + quad) ^ (l15 & 7)) << 4)); \
            o[j] = __builtin_amdgcn_mfma_f32_16x16x32_bf16(ap0, bv0, o[j], 0, 0, 0);  \
            o[j] = __builtin_amdgcn_mfma_f32_16x16x32_bf16(ap1, bv1, o[j], 0, 0, 0);  \
        }                                                                             \
    }

    STAGE(Ks0, Vt0, 0);

    f32x4 o[8] = {};
    float l_i[4] = {};
    ushort_t* Pw = &Ps[wave][0];

    for (int kt = 0; kt < 16; kt += 2) {
        __syncthreads();
        STAGE(Ks1, Vt1, kt + 1);
        FLASH_STEP(Ks0, Vt0);
        __syncthreads();
        if (kt + 2 < 16) STAGE(Ks0, Vt0, kt + 2);
        FLASH_STEP(Ks1, Vt1);
    }
#undef STAGE
#undef FLASH_STEP
#pragma unroll
    for (int r = 0; r < 4; ++r) {
        float l = l_i[r];
        l += __shfl_xor(l, 1);
        l += __shfl_xor(l, 2);
        l += __shfl_xor(l, 4);
        l += __shfl_xor(l, 8);
        l_i[r] = l;
    }
    float gsa = 1.f / (1.f + __expf(-gstr[0]));
    float blend = fminf(0.05f, gsa * 0.1f);
    int b = bh >> 4, h = bh & 15;
#pragma unroll
    for (int r = 0; r < 4; ++r) {
        int q = qt * 64 + wave * 16 + quad * 4 + r;
        const float* qaRow = qa + ((size_t)bh * 1024 + q) * 8;
        float qam[8], Z = 0.f;
#pragma unroll
        for (int n = 0; n < 8; ++n) {
            qam[n] = qaRow[n] * amp[h * 8 + n];
            Z += qam[n] * S1s[n];
        }
        float invZ = 1.f / (Z + 1e-8f);
        float invl = 1.f / l_i[r];
        ushort_t* outp = blended + ((size_t)(b * 1024 + q)) * 2048 + h * 128;
#pragma unroll
        for (int j = 0; j < 8; ++j) {
            int d = j * 16 + l15;
            float dg = 0.f;
#pragma unroll
            for (int n = 0; n < 8; ++n) dg += qam[n] * KVs[n * 128 + d];
            float v = (1.f - blend) * (o[j][r] * invl) + blend * (dg * invZ);
            outp[d] = f2b(v);
        }
    }
}

// ---------------------------------------------------------------------------
extern "C" void kernel_launch(void* const* d_in, const int* in_sizes, int n_in,
                              void* d_out, int out_size, void* d_ws, size_t ws_size,
                              hipStream_t stream) {
    const float* X = (const float*)d_in[0];
    const float* Wq = (const float*)d_in[1];
    const float* Wk = (const float*)d_in[2];
    const float* Wv = (const float*)d_in[3];
    const float* Wo = (const float*)d_in[4];
    const float* sp = (const float*)d_in[5];
    const float* sd = (const float*)d_in[6];
    const float* ls = (const float*)d_in[7];
    const float* la = (const float*)d_in[8];
    const float* dstr = (const float*)d_in[9];
    const float* gstr = (const float*)d_in[10];

    char* base = (char*)d_ws;
    ushort_t* WT4 = (ushort_t*)base;      base += 33554432;  // 4 x 2048^2 bf16
    ushort_t* Xbf = (ushort_t*)base;      base += 8388608;   // overlaid: blended
    ushort_t* blended = Xbf;                                 // Xbf dead after gemm_qkv
    ushort_t* Qbf = (ushort_t*)base;      base += 8388608;
    ushort_t* Kbf = (ushort_t*)base;      base += 8388608;
    ushort_t* Vbf = (ushort_t*)base;      base += 8388608;
    ushort_t* Vtb = (ushort_t*)base;      base += 8388608;
    float* qaw = (float*)base;            base += 1048576;
    float* posn = (float*)base;           base += 65536;
    float* dirn = (float*)base;           base += 65536;
    float* pos_sq = (float*)base;         base += 512;
    float* pdv = (float*)base;            base += 512;
    float* iv2s2 = (float*)base;          base += 512;
    float* ampw = (float*)base;           base += 512;
    float* S1p = (float*)base;            base += 16384;     // 32*8*16 fp32
    float* KVp = (float*)base;            base += 2097152;   // 32*8*16*128 fp32

    prep<<<dim3(64, 64, 5), 256, 0, stream>>>(X, Wq, Wk, Wv, Wo, sp, sd, ls, la,
                                              Xbf, WT4, posn, dirn, pos_sq, pdv, iv2s2, ampw);
    gemm_qkv<<<dim3(16, 48), 256, 0, stream>>>(Xbf, WT4, Qbf, Kbf, Vbf, Vtb);
    affinity_q<<<1024, 256, 0, stream>>>(Qbf, posn, dirn, pos_sq, pdv, iv2s2, dstr, qaw);
    kv_s1_part<<<dim3(32, 16), 128, 0, stream>>>(Kbf, Vbf, posn, dirn, pos_sq, pdv, iv2s2,
                                                 dstr, KVp, S1p);
    flash_blend<<<dim3(16, 32), 256, 0, stream>>>(Qbf, Kbf, Vtb, qaw, ampw, S1p, KVp,
                                                  gstr, blended);
    gemm_out<<<dim3(16, 32), 256, 0, stream>>>(blended, WT4 + 12582912, (float*)d_out);
}